// Round 2
// baseline (4036.567 us; speedup 1.0000x reference)
//
#include <hip/hip_runtime.h>
#include <cstdint>

typedef unsigned short u16;
typedef __attribute__((ext_vector_type(8))) short s16x8;   // 8 bf16 (4 VGPRs)
typedef __attribute__((ext_vector_type(4))) float f32x4;   // MFMA C/D frag

#define T_LEN 256
#define BATCH 64
#define HID   1024
#define NWG   64          // recurrence workgroups (one per 16-wide h slice)
#define WLDS_K 1032       // 1024 + 8 pad elements (16B) -> conflict-free ds_read_b128

// ---------- bf16 helpers (raw u16 storage; RNE convert) ----------
__device__ __forceinline__ float b2f(u16 u) {
    union { unsigned u; float f; } v; v.u = ((unsigned)u) << 16; return v.f;
}
__device__ __forceinline__ u16 f2b(float f) {
    union { float f; unsigned u; } v; v.f = f;
    unsigned u = v.u;
    return (u16)((u + 0x7fffu + ((u >> 16) & 1u)) >> 16);
}
__device__ __forceinline__ float sigmoidf_(float x) { return 1.0f / (1.0f + __expf(-x)); }
__device__ __forceinline__ float tanhf_(float x) {
    float e = __expf(2.0f * x);
    return 1.0f - 2.0f / (e + 1.0f);   // robust at +/-inf
}

// ---------- fp32 -> bf16 bulk convert (vectorized) ----------
__global__ __launch_bounds__(256) void f32_to_bf16(const float4* __restrict__ in,
                                                   ushort4* __restrict__ out, int n4) {
    int i = blockIdx.x * 256 + threadIdx.x;
    if (i < n4) {
        float4 v = in[i];
        ushort4 o;
        o.x = f2b(v.x); o.y = f2b(v.y); o.z = f2b(v.z); o.w = f2b(v.w);
        out[i] = o;
    }
}

// ---------- transpose 1024x1024: out_bf16[c][r] = (bf16)in_f32[r][c] ----------
__global__ __launch_bounds__(256) void transpose_f32_bf16(const float* __restrict__ in,
                                                          u16* __restrict__ out) {
    __shared__ u16 tile[64][65];
    int tx = threadIdx.x & 63, ty = threadIdx.x >> 6;
    int r0 = blockIdx.y * 64, c0 = blockIdx.x * 64;
    #pragma unroll
    for (int r = ty; r < 64; r += 4)
        tile[r][tx] = f2b(in[(size_t)(r0 + r) * 1024 + c0 + tx]);
    __syncthreads();
    #pragma unroll
    for (int c = ty; c < 64; c += 4)
        out[(size_t)(c0 + c) * 1024 + r0 + tx] = tile[tx][c];
}

// ---------- init: zero barrier counter, HsBuf[0] = (bf16)H0 ----------
__global__ void init_misc(const float* __restrict__ H0, u16* __restrict__ HsBuf,
                          unsigned* __restrict__ counter) {
    int i = blockIdx.x * 256 + threadIdx.x;
    if (i == 0) *counter = 0u;
    if (i < BATCH * HID) HsBuf[i] = f2b(H0[i]);
}

// ---------- GEMM: C[m][col] = A[m][:] . BT[col][:] + bias[col]
// A [M][K] bf16 row-major, BT [N][K] bf16 row-major, fp32 acc.
// Output: Cf (fp32) if non-null, else Cb (bf16). 128x128 tile, BK=32, 4 waves of 64x64.
__global__ __launch_bounds__(256) void gemm_bt(const u16* __restrict__ A,
                                               const u16* __restrict__ BT,
                                               const float* __restrict__ bias,
                                               u16* __restrict__ Cb,
                                               float* __restrict__ Cf,
                                               int M, int K, int ldc) {
    __shared__ __align__(16) u16 As[128 * 32];  // [m][k], 64B rows
    __shared__ __align__(16) u16 Bs[128 * 32];  // [n][k]
    const int tid  = threadIdx.x;
    const int lane = tid & 63;
    const int w    = tid >> 6;
    const int wm   = (w >> 1) * 64;
    const int wn   = (w & 1) * 64;
    const long m0 = (long)blockIdx.x * 128;
    const long n0 = (long)blockIdx.y * 128;
    const int lrow = lane & 15;
    const int lq   = lane >> 4;

    f32x4 acc[4][4];
    const f32x4 vzero = {0.f, 0.f, 0.f, 0.f};
    #pragma unroll
    for (int i = 0; i < 4; ++i)
        #pragma unroll
        for (int j = 0; j < 4; ++j) acc[i][j] = vzero;

    for (int k0 = 0; k0 < K; k0 += 32) {
        __syncthreads();
        #pragma unroll
        for (int i = 0; i < 2; ++i) {
            int chunk = i * 256 + w * 64 + lane;   // 16B chunk id, 0..511
            const u16* ga = A + (m0 + (chunk >> 2)) * (long)K + k0 + (chunk & 3) * 8;
            __builtin_amdgcn_global_load_lds(
                (const __attribute__((address_space(1))) unsigned int*)ga,
                (__attribute__((address_space(3))) unsigned int*)(As + (i * 256 + w * 64) * 8),
                16, 0, 0);
            const u16* gb = BT + (n0 + (chunk >> 2)) * (long)K + k0 + (chunk & 3) * 8;
            __builtin_amdgcn_global_load_lds(
                (const __attribute__((address_space(1))) unsigned int*)gb,
                (__attribute__((address_space(3))) unsigned int*)(Bs + (i * 256 + w * 64) * 8),
                16, 0, 0);
        }
        __syncthreads();
        s16x8 af[4], bf[4];
        #pragma unroll
        for (int i = 0; i < 4; ++i)
            af[i] = *(const s16x8*)(As + (wm + i * 16 + lrow) * 32 + lq * 8);
        #pragma unroll
        for (int j = 0; j < 4; ++j)
            bf[j] = *(const s16x8*)(Bs + (wn + j * 16 + lrow) * 32 + lq * 8);
        #pragma unroll
        for (int i = 0; i < 4; ++i)
            #pragma unroll
            for (int j = 0; j < 4; ++j)
                acc[i][j] = __builtin_amdgcn_mfma_f32_16x16x32_bf16(af[i], bf[j], acc[i][j], 0, 0, 0);
    }
    // epilogue: + bias. C/D frag: col=lane&15, row=(lane>>4)*4+r
    #pragma unroll
    for (int j = 0; j < 4; ++j) {
        long col = n0 + wn + j * 16 + lrow;
        float bv = bias[col];
        #pragma unroll
        for (int i = 0; i < 4; ++i) {
            long rowb = m0 + wm + i * 16 + lq * 4;
            #pragma unroll
            for (int r = 0; r < 4; ++r) {
                float v = acc[i][j][r] + bv;
                if (Cf) Cf[(rowb + r) * (long)ldc + col] = v;
                else    Cb[(rowb + r) * (long)ldc + col] = f2b(v);
            }
        }
    }
}

// ---------- persistent LSTM recurrence: 64 WGs, 1 barrier/step ----------
// WG j owns h in [16j,16j+16) x all 4 gates (LDS-stationary W slice, [c=g*16+hi][k]).
// Wave w owns batches [16w,16w+16). C carry lives in registers.
__global__ __launch_bounds__(256) void lstm_steps(const u16* __restrict__ Xall,   // [T*B][4096] col=g*1024+h
                                                  const u16* __restrict__ WThT,   // 4x [h][k] contiguous (hi,hf,ho,hc)
                                                  const float* __restrict__ C0,
                                                  u16* __restrict__ HsBuf,        // [257][64][1024] bf16
                                                  float* __restrict__ out,        // d_out (fp32)
                                                  unsigned* __restrict__ counter) {
    extern __shared__ u16 Wlds[];   // [64][WLDS_K]
    const int tid  = threadIdx.x;
    const int lane = tid & 63;
    const int w    = tid >> 6;
    const int j    = blockIdx.x;
    const int lrow = lane & 15;
    const int lq   = lane >> 4;

    // stage W slice: row c = g*16+hi <- WT_g[16j+hi][:]
    for (int idx = tid; idx < 64 * 128; idx += 256) {
        int c = idx >> 7, kc16 = idx & 127;
        int g = c >> 4, hi = c & 15;
        const uint4* src = (const uint4*)(WThT + (size_t)g * 1048576 +
                                          (size_t)(16 * j + hi) * 1024 + kc16 * 8);
        *(uint4*)(Wlds + c * WLDS_K + kc16 * 8) = *src;
    }

    const int h = 16 * j + lrow;
    float c_reg[4];
    #pragma unroll
    for (int r = 0; r < 4; ++r) {
        int b = 16 * w + lq * 4 + r;
        c_reg[r] = C0[b * 1024 + h];
    }
    __syncthreads();

    unsigned target = 0;
    for (int t = 0; t < T_LEN; ++t) {
        const u16* Hrow = HsBuf + (size_t)t * (BATCH * HID);
        f32x4 acc[4];
        #pragma unroll
        for (int g = 0; g < 4; ++g) {
            #pragma unroll
            for (int r = 0; r < 4; ++r) {
                int b = 16 * w + lq * 4 + r;
                acc[g][r] = b2f(Xall[((size_t)t * 64 + b) * 4096 + g * 1024 + h]);
            }
        }
        const u16* arow = Hrow + (16 * w + lrow) * 1024 + lq * 8;
        s16x8 a_next = *(const s16x8*)(arow);
        #pragma unroll 4
        for (int kc = 0; kc < 32; ++kc) {
            s16x8 a = a_next;
            if (kc < 31) a_next = *(const s16x8*)(arow + (kc + 1) * 32);
            #pragma unroll
            for (int g = 0; g < 4; ++g) {
                s16x8 bfr = *(const s16x8*)(Wlds + (g * 16 + lrow) * WLDS_K + kc * 32 + lq * 8);
                acc[g] = __builtin_amdgcn_mfma_f32_16x16x32_bf16(a, bfr, acc[g], 0, 0, 0);
            }
        }
        u16 hn_bf[4];
        float hn_f[4];
        #pragma unroll
        for (int r = 0; r < 4; ++r) {
            float ig = sigmoidf_(acc[0][r]);
            float fg = sigmoidf_(acc[1][r]);
            float og = sigmoidf_(acc[2][r]);
            float ct = tanhf_(acc[3][r]);
            float cn = fg * c_reg[r] + ig * ct;
            c_reg[r] = cn;
            hn_f[r]  = og * tanhf_(cn);
            hn_bf[r] = f2b(hn_f[r]);
        }
        u16* Hnext = HsBuf + (size_t)(t + 1) * (BATCH * HID);
        #pragma unroll
        for (int r = 0; r < 4; ++r) {
            int b = 16 * w + lq * 4 + r;
            Hnext[b * 1024 + h] = hn_bf[r];
        }
        if (t == T_LEN - 1) {
            #pragma unroll
            for (int r = 0; r < 4; ++r) {
                int b = 16 * w + lq * 4 + r;
                out[16777216 + b * 1024 + h] = hn_f[r];              // Hf (fp32)
                out[16777216 + 65536 + b * 1024 + h] = c_reg[r];     // Cf (fp32)
            }
            break;  // no barrier needed after last step
        }
        // device-scope barrier (monotonic counter; 64 co-resident WGs)
        target += NWG;
        __syncthreads();
        if (tid == 0) {
            __threadfence();  // release Hnext stores
            __hip_atomic_fetch_add(counter, 1u, __ATOMIC_RELAXED, __HIP_MEMORY_SCOPE_AGENT);
            while (__hip_atomic_load(counter, __ATOMIC_RELAXED, __HIP_MEMORY_SCOPE_AGENT) < target)
                __builtin_amdgcn_s_sleep(1);
            __threadfence();  // acquire
        }
        __syncthreads();
    }
}

// ---------- workspace layout (bytes) ----------
//   0         : unsigned counter (256B reserved)
//   256       : 9 transposed bf16 weights, 2MB each: WxiT,WxfT,WxoT,WxcT,WhiT,WhfT,WhoT,WhcT,WhqT
//   18874624  : Xbf  bf16 [16384][1024]       (33,554,432 B)  -- inputs converted
//   52429056  : Xall bf16 [16384][4096]       (134,217,728 B)
//   186646784 : HsBuf bf16 [257][64][1024]    (33,685,504 B)
//   total ~210.1 MB
extern "C" void kernel_launch(void* const* d_in, const int* in_sizes, int n_in,
                              void* d_out, int out_size, void* d_ws, size_t ws_size,
                              hipStream_t stream) {
    const float* inputs = (const float*)d_in[0];
    const float* H0   = (const float*)d_in[1];
    const float* C0   = (const float*)d_in[2];
    const float* W_xi = (const float*)d_in[3];
    const float* W_hi = (const float*)d_in[4];
    const float* b_i  = (const float*)d_in[5];
    const float* W_xf = (const float*)d_in[6];
    const float* W_hf = (const float*)d_in[7];
    const float* b_f  = (const float*)d_in[8];
    const float* W_xo = (const float*)d_in[9];
    const float* W_ho = (const float*)d_in[10];
    const float* b_o  = (const float*)d_in[11];
    const float* W_xc = (const float*)d_in[12];
    const float* W_hc = (const float*)d_in[13];
    const float* b_c  = (const float*)d_in[14];
    const float* W_hq = (const float*)d_in[15];
    const float* b_q  = (const float*)d_in[16];

    float* out = (float*)d_out;
    char* ws = (char*)d_ws;
    unsigned* counter = (unsigned*)ws;
    u16* WT    = (u16*)(ws + 256);
    u16* Xbf   = (u16*)(ws + 18874624);
    u16* Xall  = (u16*)(ws + 52429056);
    u16* HsBuf = (u16*)(ws + 186646784);

    // inputs fp32 -> bf16 (16M elements, 4M float4)
    f32_to_bf16<<<16384, 256, 0, stream>>>((const float4*)inputs, (ushort4*)Xbf, 4194304);

    const float* wsrcs[9] = {W_xi, W_xf, W_xo, W_xc, W_hi, W_hf, W_ho, W_hc, W_hq};
    for (int i = 0; i < 9; ++i)
        transpose_f32_bf16<<<dim3(16, 16), 256, 0, stream>>>(wsrcs[i], WT + (size_t)i * 1048576);

    init_misc<<<256, 256, 0, stream>>>(H0, HsBuf, counter);

    const float* biases[4] = {b_i, b_f, b_o, b_c};
    for (int g = 0; g < 4; ++g)
        gemm_bt<<<dim3(128, 8), 256, 0, stream>>>(Xbf, WT + (size_t)g * 1048576, biases[g],
                                                  Xall + g * 1024, (float*)nullptr,
                                                  16384, 1024, 4096);

    hipFuncSetAttribute((const void*)lstm_steps, hipFuncAttributeMaxDynamicSharedMemorySize,
                        64 * WLDS_K * 2);
    lstm_steps<<<NWG, 256, 64 * WLDS_K * 2, stream>>>(Xall, WT + (size_t)4 * 1048576, C0,
                                                      HsBuf, out, counter);

    // outputs = Hs @ W_hq + b_q  (fp32 out)
    gemm_bt<<<dim3(128, 8), 256, 0, stream>>>(HsBuf + 65536, WT + (size_t)8 * 1048576, b_q,
                                              (u16*)nullptr, out, 16384, 1024, 1024);
}